// Round 4
// baseline (382.785 us; speedup 1.0000x reference)
//
#include <hip/hip_runtime.h>
#include <math.h>

// NeuralMemory on MI355X — R12: full-chain fusion via scratch-frag readback.
// Insight: the epilogue scratch tile for pair pr holds exactly MFMA frag
// c=4*h2+pr for the wave's 16 tokens — one ds_read_b128 turns an epilogue
// output into the next GEMM's A-frag. fwdbwd_k fuses fwd L0 / fwd L1+bwd
// elem / bwd L0 (z0, dh2 live in packed-bf16 regs, never global); ret_k
// fuses both retrieval layers (r1 never global). 9 -> 6 dispatches,
// ~130 MB intermediate traffic removed. All math bit-identical to R11.

#define NTOK 32768
#define NM ((size_t)NTOK * 256)
#define LRc 1e-3f
#define WDc 1e-2f
#define EPSc 1e-8f

typedef __attribute__((ext_vector_type(8))) short bf16x8;
typedef __attribute__((ext_vector_type(4))) float f32x4;

__device__ __forceinline__ float b2f(unsigned short u) {
    union { unsigned int i; float f; } c;
    c.i = ((unsigned int)u) << 16;
    return c.f;
}
__device__ __forceinline__ unsigned short f2b(float f) {
    union { float f; unsigned int i; } c;
    c.f = f;
    unsigned int i = c.i;
    return (unsigned short)((i + 0x7FFFu + ((i >> 16) & 1u)) >> 16);
}
__device__ __forceinline__ float sigm(float z) { return 1.f / (1.f + __expf(-z)); }
__device__ __forceinline__ float siluf(float z) { return z * sigm(z); }
__device__ __forceinline__ float dsiluf(float z) {
    float s = sigm(z);
    return s * (1.f + z * (1.f - s));
}
__device__ __forceinline__ void unpack4(uint2 u, float* f) {
    f[0] = b2f(u.x & 0xFFFF); f[1] = b2f(u.x >> 16);
    f[2] = b2f(u.y & 0xFFFF); f[3] = b2f(u.y >> 16);
}
__device__ __forceinline__ uint2 pack4(const float* f) {
    uint2 o;
    o.x = (unsigned)f2b(f[0]) | ((unsigned)f2b(f[1]) << 16);
    o.y = (unsigned)f2b(f[2]) | ((unsigned)f2b(f[3]) << 16);
    return o;
}

#define WSTR 264   // W tile row stride in shorts (33x 16B units, odd => rotate)
#define SSTR 40    // scratch row stride in shorts (80 B, 16B-aligned)

// ---- shared building blocks for the fused kernels ----
#define FILLW(SRC)                                                         \
    {                                                                      \
        _Pragma("unroll") for (int it_ = 0; it_ < 8; it_++) {              \
            int i_ = it_ * 512 + tid;                                      \
            int row_ = i_ >> 5, g8_ = i_ & 31;                             \
            *(uint4*)&Ws[row_ * WSTR + g8_ * 8] =                          \
                *(const uint4*)((SRC) + (size_t)row_ * 256 + g8_ * 8);     \
        }                                                                  \
    }

#define MFMA_HALF(FR)                                                      \
    {                                                                      \
        _Pragma("unroll") for (int t_ = 0; t_ < 8; t_++) acc[t_] =         \
            (f32x4){0.f, 0.f, 0.f, 0.f};                                   \
        _Pragma("unroll") for (int c_ = 0; c_ < 8; c_++) {                 \
            _Pragma("unroll") for (int nt_ = 0; nt_ < 8; nt_++) {          \
                bf16x8 wf_ = *(const bf16x8*)&Ws[(nt_ * 16 + cc_) * WSTR + \
                                                 c_ * 32 + q * 8];         \
                acc[nt_] = __builtin_amdgcn_mfma_f32_16x16x32_bf16(        \
                    wf_, (FR)[c_], acc[nt_], 0, 0, 0);                     \
            }                                                              \
        }                                                                  \
    }

#define COLSUM(o, base)                                                    \
    {                                                                      \
        float s0_ = o[0], s1_ = o[1], s2_ = o[2], s3_ = o[3];              \
        _Pragma("unroll") for (int m_ = 1; m_ < 16; m_ <<= 1) {            \
            s0_ += __shfl_xor(s0_, m_);                                    \
            s1_ += __shfl_xor(s1_, m_);                                    \
            s2_ += __shfl_xor(s2_, m_);                                    \
            s3_ += __shfl_xor(s3_, m_);                                    \
        }                                                                  \
        if (cc_ == 0) {                                                    \
            atomicAdd(&accsh[(base)], s0_);                                \
            atomicAdd(&accsh[(base) + 1], s1_);                            \
            atomicAdd(&accsh[(base) + 2], s2_);                            \
            atomicAdd(&accsh[(base) + 3], s3_);                            \
        }                                                                  \
    }

// ---------------------------------------------------------------------------
// Projections: K,Q,V = X @ {Wk,Wq,Wv} in one kernel, z-loop inside block.
// ---------------------------------------------------------------------------
__global__ __launch_bounds__(512, 4) void wgemm3_k(
    const unsigned short* __restrict__ A, const unsigned short* __restrict__ wt,
    unsigned short* __restrict__ Kb, unsigned short* __restrict__ Qb,
    unsigned short* __restrict__ Vb) {
    __shared__ unsigned short Ws[128 * WSTR];
    __shared__ unsigned short Sc[8][16 * SSTR];
    const int n0 = blockIdx.x * 128, m0 = blockIdx.y * 128;
    const int tid = threadIdx.x, lane = tid & 63, wv = tid >> 6;
    const int cc_ = lane & 15, q = lane >> 4;
    const int t0 = m0 + wv * 16;

    const unsigned short* xp = A + (size_t)(t0 + cc_) * 256 + q * 8;
    bf16x8 xf[8];
#pragma unroll
    for (int c = 0; c < 8; c++) xf[c] = *(const bf16x8*)(xp + c * 32);

    unsigned short* sc = &Sc[wv][0];
    const int rtok = lane >> 2, roct = (lane & 3) * 8;
    unsigned short* const outs[3] = {Kb, Qb, Vb};
    f32x4 acc[8];

    for (int z = 0; z < 3; z++) {
        __syncthreads();  // prior z's Ws reads complete before refill
        FILLW(wt + (size_t)z * 65536 + (size_t)n0 * 256);
        __syncthreads();
        MFMA_HALF(xf);

        unsigned short* Cb = outs[z];
#pragma unroll
        for (int pr = 0; pr < 4; pr++) {
#pragma unroll
            for (int h = 0; h < 2; h++) {
                const int nt = pr * 2 + h;
                f32x4 c4 = acc[nt];
                float o[4] = {c4[0], c4[1], c4[2], c4[3]};
                *(uint2*)&sc[cc_ * SSTR + h * 16 + q * 4] = pack4(o);
            }
            uint4 pk = *(const uint4*)&sc[rtok * SSTR + roct];
            *(uint4*)(Cb + (size_t)(t0 + rtok) * 256 + n0 + pr * 32 + roct) = pk;
        }
    }
}

// ---------------------------------------------------------------------------
// Fused fwd L0 + fwd L1/bwd-elem + bwd L0. One block per 128 tokens; both
// n-halves processed sequentially per layer (64 KB W half-fills). h1/dz1
// frags chained in-register via scratch readback; z0/dh2 packed-bf16 regs.
// Writes h1b, dz1b, dz0b (for rgemm) + bias-grad colsums into gB.
// ---------------------------------------------------------------------------
__global__ __launch_bounds__(512, 2) void fwdbwd_k(
    const unsigned short* __restrict__ Kb, const unsigned short* __restrict__ Vb,
    const unsigned short* __restrict__ W0t, const unsigned short* __restrict__ W1t,
    const unsigned short* __restrict__ W1bt, const float* __restrict__ bias,
    const float* __restrict__ alr, unsigned short* __restrict__ h1b,
    unsigned short* __restrict__ dz1b, unsigned short* __restrict__ dz0b,
    float* __restrict__ gB) {
    __shared__ unsigned short Ws[128 * WSTR];
    __shared__ unsigned short Sc[8][16 * SSTR];
    __shared__ float accsh[512];
    const int tid = threadIdx.x, lane = tid & 63, wv = tid >> 6;
    const int cc_ = lane & 15, q = lane >> 4;
    const int t0 = blockIdx.x * 128 + wv * 16, tok = t0 + cc_;
    unsigned short* sc = &Sc[wv][0];
    const int rtok = lane >> 2, roct = (lane & 3) * 8;
    accsh[tid] = 0.f;

    const unsigned short* kp = Kb + (size_t)tok * 256 + q * 8;
    bf16x8 kf[8];
#pragma unroll
    for (int c = 0; c < 8; c++) kf[c] = *(const bf16x8*)(kp + c * 32);
    const float lalr = alr[tok] * (2.f / 256.f);

    uint2 zp[16], hp[16], dp[16];
    bf16x8 hf[8], df[8];
    f32x4 acc[8];

#define EPI_L0(H2)                                                            \
    {                                                                         \
        _Pragma("unroll") for (int pr = 0; pr < 4; pr++) {                    \
            _Pragma("unroll") for (int h = 0; h < 2; h++) {                   \
                const int nt = pr * 2 + h;                                    \
                const int gcol = (H2) * 128 + nt * 16 + q * 4;                \
                const size_t off = (size_t)tok * 256 + gcol;                  \
                f32x4 c4 = acc[nt];                                           \
                float bv[4], a[4], o[4], zz[4];                               \
                *(float4*)bv = *(const float4*)(bias + gcol);                 \
                unpack4(*(const uint2*)(Kb + off), a);                        \
                _Pragma("unroll") for (int r = 0; r < 4; r++) {               \
                    float z = c4[r] + bv[r];                                  \
                    zz[r] = z;                                                \
                    o[r] = a[r] + siluf(z);                                   \
                }                                                             \
                zp[(H2) * 8 + pr * 2 + h] = pack4(zz);                        \
                uint2 po = pack4(o);                                          \
                hp[(H2) * 8 + pr * 2 + h] = po;                               \
                *(uint2*)&sc[cc_ * SSTR + h * 16 + q * 4] = po;               \
            }                                                                 \
            uint4 pk = *(const uint4*)&sc[rtok * SSTR + roct];                \
            *(uint4*)(h1b + (size_t)(t0 + rtok) * 256 + (H2) * 128 +          \
                      pr * 32 + roct) = pk;                                   \
            hf[(H2) * 4 + pr] = *(const bf16x8*)&sc[cc_ * SSTR + q * 8];      \
        }                                                                     \
    }

#define EPI_L1(H2)                                                            \
    {                                                                         \
        _Pragma("unroll") for (int pr = 0; pr < 4; pr++) {                    \
            _Pragma("unroll") for (int h = 0; h < 2; h++) {                   \
                const int nt = pr * 2 + h;                                    \
                const int gcol = (H2) * 128 + nt * 16 + q * 4;                \
                const size_t off = (size_t)tok * 256 + gcol;                  \
                f32x4 c4 = acc[nt];                                           \
                float bv[4], a[4], vv[4], o[4], dhv[4];                       \
                *(float4*)bv = *(const float4*)(bias + 256 + gcol);           \
                unpack4(hp[(H2) * 8 + pr * 2 + h], a);                        \
                unpack4(*(const uint2*)(Vb + off), vv);                       \
                _Pragma("unroll") for (int r = 0; r < 4; r++) {               \
                    float z = c4[r] + bv[r];                                  \
                    float h2v = a[r] + siluf(z);                              \
                    float dh = lalr * (h2v - vv[r]);                          \
                    dhv[r] = dh;                                              \
                    o[r] = dh * dsiluf(z);                                    \
                }                                                             \
                dp[(H2) * 8 + pr * 2 + h] = pack4(dhv);                       \
                *(uint2*)&sc[cc_ * SSTR + h * 16 + q * 4] = pack4(o);         \
                COLSUM(o, 256 + gcol);                                        \
            }                                                                 \
            uint4 pk = *(const uint4*)&sc[rtok * SSTR + roct];                \
            *(uint4*)(dz1b + (size_t)(t0 + rtok) * 256 + (H2) * 128 +         \
                      pr * 32 + roct) = pk;                                   \
            df[(H2) * 4 + pr] = *(const bf16x8*)&sc[cc_ * SSTR + q * 8];      \
        }                                                                     \
    }

#define EPI_L2(H2)                                                            \
    {                                                                         \
        _Pragma("unroll") for (int pr = 0; pr < 4; pr++) {                    \
            _Pragma("unroll") for (int h = 0; h < 2; h++) {                   \
                const int nt = pr * 2 + h;                                    \
                const int gcol = (H2) * 128 + nt * 16 + q * 4;                \
                f32x4 c4 = acc[nt];                                           \
                float ri[4], zi[4], o[4];                                     \
                unpack4(dp[(H2) * 8 + pr * 2 + h], ri);                       \
                unpack4(zp[(H2) * 8 + pr * 2 + h], zi);                       \
                _Pragma("unroll") for (int r = 0; r < 4; r++) o[r] =          \
                    (c4[r] + ri[r]) * dsiluf(zi[r]);                          \
                *(uint2*)&sc[cc_ * SSTR + h * 16 + q * 4] = pack4(o);         \
                COLSUM(o, gcol);                                              \
            }                                                                 \
            uint4 pk = *(const uint4*)&sc[rtok * SSTR + roct];                \
            *(uint4*)(dz0b + (size_t)(t0 + rtok) * 256 + (H2) * 128 +         \
                      pr * 32 + roct) = pk;                                   \
        }                                                                     \
    }

    // ---- fwd L0 ----
    FILLW(W0t);
    __syncthreads();
    MFMA_HALF(kf);
    __syncthreads();
    FILLW(W0t + 32768);
    EPI_L0(0);
    __syncthreads();
    MFMA_HALF(kf);
    __syncthreads();
    FILLW(W1t);
    EPI_L0(1);
    __syncthreads();
    // ---- fwd L1 + bwd elementwise ----
    MFMA_HALF(hf);
    __syncthreads();
    FILLW(W1t + 32768);
    EPI_L1(0);
    __syncthreads();
    MFMA_HALF(hf);
    __syncthreads();
    FILLW(W1bt);
    EPI_L1(1);
    __syncthreads();
    // ---- bwd L0 ----
    MFMA_HALF(df);
    __syncthreads();
    FILLW(W1bt + 32768);
    EPI_L2(0);
    __syncthreads();
    MFMA_HALF(df);
    EPI_L2(1);
    // ---- flush bias-grad colsums ----
    __syncthreads();
    atomicAdd(&gB[tid], accsh[tid]);
#undef EPI_L0
#undef EPI_L1
#undef EPI_L2
}

// ---------------------------------------------------------------------------
// Fused retrieval: out = r1 + silu(r1@nW1+nb1), r1 = Q + silu(Q@nW0+nb0).
// r1 never touches global: frags via scratch readback, residual in regs.
// ---------------------------------------------------------------------------
__global__ __launch_bounds__(512, 2) void ret_k(
    const unsigned short* __restrict__ Qb, const unsigned short* __restrict__ nW0t,
    const unsigned short* __restrict__ nW1t, const float* __restrict__ nb,
    float* __restrict__ out_ret) {
    __shared__ unsigned short Ws[128 * WSTR];
    __shared__ unsigned short Sc[8][16 * SSTR];
    const int tid = threadIdx.x, lane = tid & 63, wv = tid >> 6;
    const int cc_ = lane & 15, q = lane >> 4;
    const int t0 = blockIdx.x * 128 + wv * 16, tok = t0 + cc_;
    unsigned short* sc = &Sc[wv][0];

    const unsigned short* qp = Qb + (size_t)tok * 256 + q * 8;
    bf16x8 qf[8];
#pragma unroll
    for (int c = 0; c < 8; c++) qf[c] = *(const bf16x8*)(qp + c * 32);

    uint2 rp[16];
    bf16x8 rf[8];
    f32x4 acc[8];

#define EPI_R0(H2)                                                            \
    {                                                                         \
        _Pragma("unroll") for (int pr = 0; pr < 4; pr++) {                    \
            _Pragma("unroll") for (int h = 0; h < 2; h++) {                   \
                const int nt = pr * 2 + h;                                    \
                const int gcol = (H2) * 128 + nt * 16 + q * 4;                \
                const size_t off = (size_t)tok * 256 + gcol;                  \
                f32x4 c4 = acc[nt];                                           \
                float bv[4], a[4], o[4];                                      \
                *(float4*)bv = *(const float4*)(nb + gcol);                   \
                unpack4(*(const uint2*)(Qb + off), a);                        \
                _Pragma("unroll") for (int r = 0; r < 4; r++) o[r] =          \
                    a[r] + siluf(c4[r] + bv[r]);                              \
                uint2 po = pack4(o);                                          \
                rp[(H2) * 8 + pr * 2 + h] = po;                               \
                *(uint2*)&sc[cc_ * SSTR + h * 16 + q * 4] = po;               \
            }                                                                 \
            rf[(H2) * 4 + pr] = *(const bf16x8*)&sc[cc_ * SSTR + q * 8];      \
        }                                                                     \
    }

#define EPI_R1(H2)                                                            \
    {                                                                         \
        _Pragma("unroll") for (int pr = 0; pr < 4; pr++) {                    \
            _Pragma("unroll") for (int h = 0; h < 2; h++) {                   \
                const int nt = pr * 2 + h;                                    \
                const int gcol = (H2) * 128 + nt * 16 + q * 4;                \
                const size_t off = (size_t)tok * 256 + gcol;                  \
                f32x4 c4 = acc[nt];                                           \
                float bv[4], a[4], o[4];                                      \
                *(float4*)bv = *(const float4*)(nb + 256 + gcol);             \
                unpack4(rp[(H2) * 8 + pr * 2 + h], a);                        \
                _Pragma("unroll") for (int r = 0; r < 4; r++) o[r] =          \
                    a[r] + siluf(c4[r] + bv[r]);                              \
                *(float4*)(out_ret + off) = *(float4*)o;                      \
            }                                                                 \
        }                                                                     \
    }

    FILLW(nW0t);
    __syncthreads();
    MFMA_HALF(qf);
    __syncthreads();
    FILLW(nW0t + 32768);
    EPI_R0(0);
    __syncthreads();
    MFMA_HALF(qf);
    __syncthreads();
    FILLW(nW1t);
    EPI_R0(1);
    __syncthreads();
    MFMA_HALF(rf);
    __syncthreads();
    FILLW(nW1t + 32768);
    EPI_R1(0);
    __syncthreads();
    MFMA_HALF(rf);
    EPI_R1(1);
#undef EPI_R0
#undef EPI_R1
}

// ---------------------------------------------------------------------------
// Reduction GEMM (weight grads): C[i][j] = sum_t A[t][i] B[t][j], split-K 32.
// Conflict-free swizzled transpose staging + prefetch + 8 waves/block (R9).
// ---------------------------------------------------------------------------
__global__ __launch_bounds__(512, 4) void rgemm_k(
    const unsigned short* __restrict__ Kb, const unsigned short* __restrict__ h1b,
    const unsigned short* __restrict__ dz0b,
    const unsigned short* __restrict__ dz1b, float* __restrict__ pbuf) {
    __shared__ unsigned short As[128 * 64];
    __shared__ unsigned short Bs2[128 * 64];
    const int z = blockIdx.z, layer = z >> 5, zc = z & 31;
    const unsigned short* Ag = layer ? h1b : Kb;
    const unsigned short* Bg = layer ? dz1b : dz0b;
    const int t0 = zc * 1024;
    const int j0 = blockIdx.x * 128, i0 = blockIdx.y * 128;
    const int tid = threadIdx.x, lane = tid & 63, wave = tid >> 6;

    // staging role: threads 0-255 stage A, 256-511 stage B
    const int half = tid >> 8;
    const int t9 = tid & 255;
    const int ptq = t9 >> 4;          // token pair 0..15
    const int pi = (t9 & 15) * 8;     // col group base
    const unsigned short* sg = half ? Bg : Ag;
    const int nb = half ? j0 : i0;
    unsigned int* dst = (unsigned int*)(half ? Bs2 : As);
    const unsigned short* gp = sg + (size_t)(t0 + ptq * 2) * 256 + nb + pi;

    // wave output tile: 64 rows (i) x 32 cols (j)
    const int wr = (wave >> 2) * 64, wc = (wave & 3) * 32;
    const int fr = lane & 15, fkb = lane >> 4;

    f32x4 acc[4][2];
#pragma unroll
    for (int i = 0; i < 4; i++)
#pragma unroll
        for (int j = 0; j < 2; j++) acc[i][j] = (f32x4){0.f, 0.f, 0.f, 0.f};

    uint4 u0 = *(const uint4*)gp;
    uint4 u1 = *(const uint4*)(gp + 256);
    gp += 32 * 256;

    for (int it = 0; it < 32; it++) {
        // transpose-write: pack (token 2q, 2q+1) per col, swizzled slot
        const unsigned int* w0 = (const unsigned int*)&u0;
        const unsigned int* w1 = (const unsigned int*)&u1;
#pragma unroll
        for (int ii = 0; ii < 8; ii++) {
            unsigned int lo = (w0[ii >> 1] >> (16 * (ii & 1))) & 0xFFFFu;
            unsigned int hi = (w1[ii >> 1] >> (16 * (ii & 1))) & 0xFFFFu;
            const int col = pi + ii;
            const int s2 = ((col >> 3) ^ col) & 3;
            const int s4 = ((col >> 2) ^ (col >> 5)) & 1;
            dst[col * 32 + (ptq ^ (s2 << 2) ^ (s4 << 4))] = lo | (hi << 16);
        }
        __syncthreads();
        if (it < 31) {  // prefetch next K-chunk; latency hides under MFMA phase
            u0 = *(const uint4*)gp;
            u1 = *(const uint4*)(gp + 256);
            gp += 32 * 256;
        }
        bf16x8 af[4], bfr[2];
#pragma unroll
        for (int i = 0; i < 4; i++) {
            const int col = wr + i * 16 + fr;
            const int s2 = ((col >> 3) ^ col) & 3;
            const int s4 = ((col >> 2) ^ (col >> 5)) & 1;
            af[i] = *(const bf16x8*)&As[col * 64 + (fkb ^ s2 ^ (s4 << 2)) * 8];
        }
#pragma unroll
        for (int j = 0; j < 2; j++) {
            const int col = wc + j * 16 + fr;
            const int s2 = ((col >> 3) ^ col) & 3;
            const int s4 = ((col >> 2) ^ (col >> 5)) & 1;
            bfr[j] = *(const bf16x8*)&Bs2[col * 64 + (fkb ^ s2 ^ (s4 << 2)) * 8];
        }
#pragma unroll
        for (int i = 0; i < 4; i++)
#pragma unroll
            for (int j = 0; j < 2; j++)
                acc[i][j] = __builtin_amdgcn_mfma_f32_16x16x32_bf16(
                    af[i], bfr[j], acc[i][j], 0, 0, 0);
        __syncthreads();
    }

    float* P = pbuf + (size_t)((layer << 5) + zc) * 65536;
    const int r0 = fkb * 4;
#pragma unroll
    for (int mi = 0; mi < 4; mi++)
#pragma unroll
        for (int ni = 0; ni < 2; ni++) {
            f32x4 c = acc[mi][ni];
#pragma unroll
            for (int r = 0; r < 4; r++)
                P[(size_t)(i0 + wr + mi * 16 + r0 + r) * 256 +
                  (j0 + wc + ni * 16 + fr)] = c[r];
        }
}

// ---------------------------------------------------------------------------
// gradstep: reduce pbuf (32 chunks) -> g; surprises; AdamW for W and b.
// ---------------------------------------------------------------------------
__global__ __launch_bounds__(256) void gradstep_k(
    const float* __restrict__ pbuf, const float* __restrict__ Ws,
    const float* __restrict__ bs, const float* __restrict__ accB,
    unsigned short* __restrict__ nWt, float* __restrict__ nb,
    float* __restrict__ outSW, float* __restrict__ outSb) {
    const int bi = blockIdx.x;
    if (bi < 512) {
        const int idx = bi * 256 + threadIdx.x;  // 0..131071
        const int layer = idx >> 16, rc = idx & 65535;
        const float* p = pbuf + (size_t)layer * 32 * 65536 + rc;
        float g = 0.f;
#pragma unroll 8
        for (int c = 0; c < 32; c++) g += p[(size_t)c * 65536];
        outSW[idx] = -g;
        float nw = Ws[idx] * (1.f - LRc * WDc) - LRc * g / (fabsf(g) + EPSc);
        const int l = idx >> 16, k = (idx >> 8) & 255, n = idx & 255;
        nWt[(size_t)l * 65536 + n * 256 + k] = f2b(nw);
    } else {
        for (int i = threadIdx.x; i < 512; i += 256) {
            float g = accB[i];
            outSb[i] = -g;
            nb[i] = bs[i] * (1.f - LRc * WDc) - LRc * g / (fabsf(g) + EPSc);
        }
    }
}

// ---------------------------------------------------------------------------
// prep_all: blocks 0..8191  -> x fp32 -> xb bf16 + alr (one wave per row)
//           blocks 8192..9727 -> weight transpose+cvt (z=0..4) / cvt (z=5)
//           block 9728      -> zero accB[512]
// ---------------------------------------------------------------------------
__global__ __launch_bounds__(256) void prep_all_k(
    const float* __restrict__ x, const float* __restrict__ Wlr,
    const float* __restrict__ blr, const float* __restrict__ Wk,
    const float* __restrict__ Wq, const float* __restrict__ Wv,
    const float* __restrict__ Ws, unsigned short* __restrict__ xb,
    float* __restrict__ alr, unsigned short* __restrict__ wt,
    float* __restrict__ accB) {
    const int bi = blockIdx.x;
    if (bi < 8192) {
        const int wave = threadIdx.x >> 6, lane = threadIdx.x & 63;
        const int r = bi * 4 + wave;
        float4 w = *(const float4*)(Wlr + lane * 4);
        float4 v = *(const float4*)(x + (size_t)r * 256 + lane * 4);
        float s = v.x * w.x + v.y * w.y + v.z * w.z + v.w * w.w;
        unsigned int p0 = (unsigned int)f2b(v.x) | ((unsigned int)f2b(v.y) << 16);
        unsigned int p1 = (unsigned int)f2b(v.z) | ((unsigned int)f2b(v.w) << 16);
        *(uint2*)(xb + (size_t)r * 256 + lane * 4) = make_uint2(p0, p1);
#pragma unroll
        for (int off = 32; off; off >>= 1) s += __shfl_down(s, off);
        if (lane == 0) alr[r] = 0.1f * sigm(s + blr[0]);
    } else if (bi < 9728) {
        const int b = bi - 8192;
        const int z = b >> 8;
        const int idx = (b & 255) * 256 + threadIdx.x;  // 0..65535
        const float* src = z == 0 ? Wk : z == 1 ? Wq : z == 2 ? Wv
                         : z == 3 ? Ws : Ws + 65536;
        unsigned short* dst = wt + (size_t)z * 65536;
        float v = src[idx];
        if (z == 5)
            dst[idx] = f2b(v);
        else
            dst[(idx & 255) * 256 + (idx >> 8)] = f2b(v);
    } else {
        accB[threadIdx.x] = 0.f;
        accB[threadIdx.x + 256] = 0.f;
    }
}

extern "C" void kernel_launch(void* const* d_in, const int* in_sizes, int n_in,
                              void* d_out, int out_size, void* d_ws,
                              size_t ws_size, hipStream_t stream) {
    const float* x = (const float*)d_in[0];
    const float* Wk = (const float*)d_in[1];
    const float* Wq = (const float*)d_in[2];
    const float* Wv = (const float*)d_in[3];
    const float* Wlr = (const float*)d_in[4];
    const float* blr = (const float*)d_in[5];
    const float* Ws = (const float*)d_in[6];
    const float* bs = (const float*)d_in[7];

    unsigned short* S = (unsigned short*)d_ws;
    unsigned short* xb = S + 0 * NM;
    unsigned short* Kb = S + 1 * NM;
    unsigned short* Qb = S + 2 * NM;
    unsigned short* Vb = S + 3 * NM;
    unsigned short* h1b = S + 5 * NM;
    unsigned short* dz1b = S + 6 * NM;
    unsigned short* dz0b = S + 8 * NM;
    float* pbuf = (float*)(S + 9 * NM);  // 16 MB (slot 9): 2 layers x 32 chunks

    unsigned short* wt = S + 11 * NM;
    unsigned short* W0t = wt + 3 * 65536;
    unsigned short* W1t = wt + 4 * 65536;
    unsigned short* W1b = wt + 5 * 65536;
    unsigned short* nW0t = wt + 6 * 65536;
    unsigned short* nW1t = wt + 7 * 65536;
    float* ft = (float*)(wt + 8 * 65536);
    float* alr = ft;              // 32768
    float* accB = ft + 32768;     // 512
    float* nb = accB + 512;       // 512

    float* out_ret = (float*)d_out;
    float* out_sW = out_ret + NM;
    float* out_sb = out_sW + 131072;

    dim3 blk5(512);
    dim3 blk(256);

    // prep: x->bf16 + alr, weight transpose/cvt, zero accB (one dispatch)
    prep_all_k<<<9729, blk, 0, stream>>>(x, Wlr, blr, Wk, Wq, Wv, Ws, xb, alr,
                                         wt, accB);

    // projections K,Q,V: one dispatch, z-loop inside block
    wgemm3_k<<<dim3(2, 256), blk5, 0, stream>>>(xb, wt, Kb, Qb, Vb);

    // fused fwd L0 / fwd L1 + bwd elem / bwd L0 (+ bias-grad colsums)
    fwdbwd_k<<<256, blk5, 0, stream>>>(Kb, Vb, W0t, W1t, W1b, bs, alr, h1b,
                                       dz1b, dz0b, accB);

    // weight grads: swizzled transpose-on-load split-K partials
    rgemm_k<<<dim3(2, 2, 64), blk5, 0, stream>>>(Kb, h1b, dz0b, dz1b, pbuf);

    // reduce + surprises + AdamW (W and b) in one dispatch
    gradstep_k<<<513, blk, 0, stream>>>(pbuf, Ws, bs, accB, nW0t, nb, out_sW,
                                        out_sb);

    // fused retrieval (both layers, r1 in-register)
    ret_k<<<256, blk5, 0, stream>>>(Qb, nW0t, nW1t, nb, out_ret);
}

// Round 6
// 247.743 us; speedup vs baseline: 1.5451x; 1.5451x over previous
//
#include <hip/hip_runtime.h>
#include <math.h>

// NeuralMemory on MI355X — R13 (resubmit; round-5 bench was an infra flake:
// "container failed twice", no kernel error). Revert R12's over-fusion, fuse
// x-prep into projections. R12 post-mortem: fwdbwd_k needed ~220 VGPRs in a
// 128-cap -> scratch spills + 1-block/CU serial chain = 154 us (MfmaUtil
// 3.2%). R13 is the verified R11 structure; wgemm3_k now reads x fp32
// directly (converts in-register, computes alr via LDS-resident Wlr),
// deleting the 48 MB xb staging roundtrip; prep dispatch is weights-only.

#define NTOK 32768
#define NM ((size_t)NTOK * 256)
#define LRc 1e-3f
#define WDc 1e-2f
#define EPSc 1e-8f

typedef __attribute__((ext_vector_type(8))) short bf16x8;
typedef __attribute__((ext_vector_type(4))) float f32x4;

__device__ __forceinline__ float b2f(unsigned short u) {
    union { unsigned int i; float f; } c;
    c.i = ((unsigned int)u) << 16;
    return c.f;
}
__device__ __forceinline__ unsigned short f2b(float f) {
    union { float f; unsigned int i; } c;
    c.f = f;
    unsigned int i = c.i;
    return (unsigned short)((i + 0x7FFFu + ((i >> 16) & 1u)) >> 16);
}
__device__ __forceinline__ float sigm(float z) { return 1.f / (1.f + __expf(-z)); }
__device__ __forceinline__ float siluf(float z) { return z * sigm(z); }
__device__ __forceinline__ float dsiluf(float z) {
    float s = sigm(z);
    return s * (1.f + z * (1.f - s));
}
__device__ __forceinline__ void unpack4(uint2 u, float* f) {
    f[0] = b2f(u.x & 0xFFFF); f[1] = b2f(u.x >> 16);
    f[2] = b2f(u.y & 0xFFFF); f[3] = b2f(u.y >> 16);
}
__device__ __forceinline__ uint2 pack4(const float* f) {
    uint2 o;
    o.x = (unsigned)f2b(f[0]) | ((unsigned)f2b(f[1]) << 16);
    o.y = (unsigned)f2b(f[2]) | ((unsigned)f2b(f[3]) << 16);
    return o;
}

#define WSTR 264   // W tile row stride in shorts (33x 16B units, odd => rotate)
#define SSTR 40    // scratch row stride in shorts (80 B, 16B-aligned)

// ---------------------------------------------------------------------------
// Projections: K,Q,V = X @ {Wk,Wq,Wv} in one kernel, z-loop inside block.
// R13: reads x fp32 directly (frag-shaped, 128B-contiguous per token),
// converts to bf16 in-register (same f2b bits as the old staging pass), and
// computes alr = 0.1*sigmoid(x@Wlr+blr) from LDS-resident Wlr (n0==0 writes).
// ---------------------------------------------------------------------------
__global__ __launch_bounds__(512, 4) void wgemm3_k(
    const float* __restrict__ x, const float* __restrict__ Wlr,
    const float* __restrict__ blr, const unsigned short* __restrict__ wt,
    unsigned short* __restrict__ Kb, unsigned short* __restrict__ Qb,
    unsigned short* __restrict__ Vb, float* __restrict__ alr) {
    __shared__ unsigned short Ws[128 * WSTR];
    __shared__ unsigned short Sc[8][16 * SSTR];
    __shared__ float Ls[256];
    const int n0 = blockIdx.x * 128, m0 = blockIdx.y * 128;
    const int tid = threadIdx.x, lane = tid & 63, wv = tid >> 6;
    const int cc = lane & 15, q = lane >> 4;
    const int t0 = m0 + wv * 16, tok = t0 + cc;

    if (tid < 256) Ls[tid] = Wlr[tid];
    __syncthreads();  // Ls ready before the dot below

    // ---- X-frag load (fp32) + convert + alr partial dot
    const float* xp = x + (size_t)tok * 256 + q * 8;
    bf16x8 xf[8];
    float s = 0.f;
#pragma unroll
    for (int c = 0; c < 8; c++) {
        float xv[8];
        *(float4*)&xv[0] = *(const float4*)(xp + c * 32);
        *(float4*)&xv[4] = *(const float4*)(xp + c * 32 + 4);
        float wl[8];
        *(float4*)&wl[0] = *(const float4*)&Ls[c * 32 + q * 8];
        *(float4*)&wl[4] = *(const float4*)&Ls[c * 32 + q * 8 + 4];
        unsigned short us[8];
#pragma unroll
        for (int j = 0; j < 8; j++) {
            s += xv[j] * wl[j];
            us[j] = f2b(xv[j]);
        }
        xf[c] = *(bf16x8*)us;
    }
    s += __shfl_xor(s, 16);
    s += __shfl_xor(s, 32);
    if (n0 == 0 && q == 0) alr[tok] = 0.1f * sigm(s + blr[0]);

    unsigned short* sc = &Sc[wv][0];
    const int rtok = lane >> 2, roct = (lane & 3) * 8;
    unsigned short* const outs[3] = {Kb, Qb, Vb};

    for (int z = 0; z < 3; z++) {
        __syncthreads();  // prior z's Ws reads complete before refill
#pragma unroll
        for (int it = 0; it < 8; it++) {
            int i = it * 512 + tid;
            int row = i >> 5, g8 = i & 31;
            *(uint4*)&Ws[row * WSTR + g8 * 8] =
                *(const uint4*)(wt + (size_t)z * 65536 +
                                (size_t)(n0 + row) * 256 + g8 * 8);
        }
        __syncthreads();

        f32x4 acc[8];
#pragma unroll
        for (int t = 0; t < 8; t++) acc[t] = (f32x4){0.f, 0.f, 0.f, 0.f};
#pragma unroll
        for (int c = 0; c < 8; c++) {
#pragma unroll
            for (int nt = 0; nt < 8; nt++) {
                bf16x8 wf =
                    *(const bf16x8*)&Ws[(nt * 16 + cc) * WSTR + c * 32 + q * 8];
                acc[nt] = __builtin_amdgcn_mfma_f32_16x16x32_bf16(wf, xf[c],
                                                                  acc[nt], 0, 0, 0);
            }
        }

        unsigned short* Cb = outs[z];
#pragma unroll
        for (int pr = 0; pr < 4; pr++) {
#pragma unroll
            for (int h = 0; h < 2; h++) {
                const int nt = pr * 2 + h;
                f32x4 c4 = acc[nt];
                float o[4] = {c4[0], c4[1], c4[2], c4[3]};
                *(uint2*)&sc[cc * SSTR + h * 16 + q * 4] = pack4(o);
            }
            uint4 pk = *(const uint4*)&sc[rtok * SSTR + roct];
            *(uint4*)(Cb + (size_t)(t0 + rtok) * 256 + n0 + pr * 32 + roct) = pk;
        }
    }
}

// ---------------------------------------------------------------------------
// Operand-swapped tall GEMM: C[M,256] = X[M,256] @ B with Bt[n][k]=B[k][n].
// EPI 1: z=acc+bias; Zout=z; Cb = X+silu(z)           fwd layer 0
// EPI 5: z=acc+bias; h2=X+silu(z); dh=alr'* (h2-V);   fwd layer 1 + bwd elem
//        dz=dh*dsilu(z); Cb=dz; Rout=dh; colsum(dz)->gB
// EPI 2: dz0=(acc+Rin)*dsilu(Zin); Cb=dz0; colsum->gB bwd layer 0
// EPI 3: Cb = X + silu(acc+bias)                      retrieved L0
// EPI 4: Cf = X + silu(acc+bias)  (fp32 out)          retrieved L1
// ---------------------------------------------------------------------------
template <int EPI>
__global__ __launch_bounds__(512, 4) void wgemm_k(
    const unsigned short* __restrict__ A, const unsigned short* __restrict__ Bt,
    const float* __restrict__ bias, const unsigned short* __restrict__ Rin,
    const unsigned short* __restrict__ Zin, const unsigned short* __restrict__ Vb,
    const float* __restrict__ alr, float* __restrict__ gB,
    unsigned short* __restrict__ Cb, float* __restrict__ Cf,
    unsigned short* __restrict__ Zout, unsigned short* __restrict__ Rout) {
    __shared__ unsigned short Ws[128 * WSTR];
    __shared__ unsigned short Sc[8][16 * SSTR];
    __shared__ float accsh[128];
    const int n0 = blockIdx.x * 128, m0 = blockIdx.y * 128;
    const int tid = threadIdx.x, lane = tid & 63, wv = tid >> 6;
    const int cc = lane & 15, q = lane >> 4;

    // ---- X-frag loads: 8 instrs off one base (imm offsets)
    const int t0 = m0 + wv * 16;
    const unsigned short* xp = A + (size_t)(t0 + cc) * 256 + q * 8;
    bf16x8 xf[8];
#pragma unroll
    for (int c = 0; c < 8; c++) xf[c] = *(const bf16x8*)(xp + c * 32);

    if (EPI == 2 || EPI == 5) {
        if (tid < 128) accsh[tid] = 0.f;
    }

    // ---- W half-tile fill: [128 n-rows][256 k] shorts, padded stride
#pragma unroll
    for (int it = 0; it < 8; it++) {
        int i = it * 512 + tid;
        int row = i >> 5, g8 = i & 31;
        *(uint4*)&Ws[row * WSTR + g8 * 8] =
            *(const uint4*)(Bt + (size_t)(n0 + row) * 256 + g8 * 8);
    }
    __syncthreads();

    f32x4 acc[8];
#pragma unroll
    for (int t = 0; t < 8; t++) acc[t] = (f32x4){0.f, 0.f, 0.f, 0.f};

#pragma unroll
    for (int c = 0; c < 8; c++) {
#pragma unroll
        for (int nt = 0; nt < 8; nt++) {
            bf16x8 wf = *(const bf16x8*)&Ws[(nt * 16 + cc) * WSTR + c * 32 + q * 8];
            acc[nt] = __builtin_amdgcn_mfma_f32_16x16x32_bf16(wf, xf[c],
                                                              acc[nt], 0, 0, 0);
        }
    }

    // ---- epilogue: lane holds token t0+cc, cols nt*16 + 4q + r (r=0..3)
    const int tok = t0 + cc;
    float lalr = 0.f;
    if (EPI == 5) lalr = alr[tok] * (2.f / 256.f);
    unsigned short* sc = &Sc[wv][0];
    const int rtok = lane >> 2, roct = (lane & 3) * 8;  // repack read indices

#pragma unroll
    for (int pr = 0; pr < 4; pr++) {  // tile pairs (2pr, 2pr+1) = 32 cols
        float o2[2][4], z2[2][4];     // primary / secondary quad outputs
#pragma unroll
        for (int h = 0; h < 2; h++) {
            const int nt = pr * 2 + h;
            const int gcol = n0 + nt * 16 + q * 4;
            const size_t off = (size_t)tok * 256 + gcol;
            f32x4 c = acc[nt];
            float v[4] = {c[0], c[1], c[2], c[3]};
            if (EPI == 1) {
                float bv[4], a[4];
                *(float4*)bv = *(const float4*)(bias + gcol);
                unpack4(*(const uint2*)(A + off), a);
#pragma unroll
                for (int r = 0; r < 4; r++) {
                    float z = v[r] + bv[r];
                    z2[h][r] = z;
                    o2[h][r] = a[r] + siluf(z);
                }
            } else if (EPI == 5) {
                float bv[4], a[4], vv[4];
                *(float4*)bv = *(const float4*)(bias + gcol);
                unpack4(*(const uint2*)(A + off), a);
                unpack4(*(const uint2*)(Vb + off), vv);
#pragma unroll
                for (int r = 0; r < 4; r++) {
                    float z = v[r] + bv[r];
                    float h2 = a[r] + siluf(z);
                    float dh = lalr * (h2 - vv[r]);
                    o2[h][r] = dh * dsiluf(z);  // dz
                    z2[h][r] = dh;              // dh
                }
            } else if (EPI == 2) {
                float ri[4], zi[4];
                unpack4(*(const uint2*)(Rin + off), ri);
                unpack4(*(const uint2*)(Zin + off), zi);
#pragma unroll
                for (int r = 0; r < 4; r++)
                    o2[h][r] = (v[r] + ri[r]) * dsiluf(zi[r]);
            } else {  // EPI 3 / 4
                float bv[4], a[4];
                *(float4*)bv = *(const float4*)(bias + gcol);
                unpack4(*(const uint2*)(A + off), a);
#pragma unroll
                for (int r = 0; r < 4; r++) o2[h][r] = a[r] + siluf(v[r] + bv[r]);
            }
            if (EPI == 4) {  // fp32 direct store: 4 lanes x 16 B = 64 B segs
                *(float4*)(Cf + off) = *(float4*)o2[h];
            }
            if (EPI == 2 || EPI == 5) {  // fused bias-grad column sums of dz
                float s0 = o2[h][0], s1 = o2[h][1], s2 = o2[h][2], s3 = o2[h][3];
#pragma unroll
                for (int m = 1; m < 16; m <<= 1) {
                    s0 += __shfl_xor(s0, m);
                    s1 += __shfl_xor(s1, m);
                    s2 += __shfl_xor(s2, m);
                    s3 += __shfl_xor(s3, m);
                }
                if (cc == 0) {
                    const int lc = nt * 16 + q * 4;
                    atomicAdd(&accsh[lc], s0);
                    atomicAdd(&accsh[lc + 1], s1);
                    atomicAdd(&accsh[lc + 2], s2);
                    atomicAdd(&accsh[lc + 3], s3);
                }
            }
        }
        if (EPI == 4) continue;
        // repack via wave-private scratch -> 64 B segment stores
#pragma unroll
        for (int h = 0; h < 2; h++)
            *(uint2*)&sc[cc * SSTR + h * 16 + q * 4] = pack4(o2[h]);
        uint4 pk = *(const uint4*)&sc[rtok * SSTR + roct];
        *(uint4*)(Cb + (size_t)(t0 + rtok) * 256 + n0 + pr * 32 + roct) = pk;
        if (EPI == 1 || EPI == 5) {  // second output (Zout / Rout)
#pragma unroll
            for (int h = 0; h < 2; h++)
                *(uint2*)&sc[cc * SSTR + h * 16 + q * 4] = pack4(z2[h]);
            uint4 pk2 = *(const uint4*)&sc[rtok * SSTR + roct];
            unsigned short* P2 = (EPI == 1) ? Zout : Rout;
            *(uint4*)(P2 + (size_t)(t0 + rtok) * 256 + n0 + pr * 32 + roct) = pk2;
        }
    }
    if (EPI == 2 || EPI == 5) {  // flush block-local col sums
        __syncthreads();
        if (tid < 128) atomicAdd(&gB[n0 + tid], accsh[tid]);
    }
}

// ---------------------------------------------------------------------------
// Reduction GEMM (weight grads): C[i][j] = sum_t A[t][i] B[t][j], split-K 32.
// Conflict-free swizzled transpose staging + prefetch + 8 waves/block (R9).
// ---------------------------------------------------------------------------
__global__ __launch_bounds__(512, 4) void rgemm_k(
    const unsigned short* __restrict__ Kb, const unsigned short* __restrict__ h1b,
    const unsigned short* __restrict__ dz0b,
    const unsigned short* __restrict__ dz1b, float* __restrict__ pbuf) {
    __shared__ unsigned short As[128 * 64];
    __shared__ unsigned short Bs2[128 * 64];
    const int z = blockIdx.z, layer = z >> 5, zc = z & 31;
    const unsigned short* Ag = layer ? h1b : Kb;
    const unsigned short* Bg = layer ? dz1b : dz0b;
    const int t0 = zc * 1024;
    const int j0 = blockIdx.x * 128, i0 = blockIdx.y * 128;
    const int tid = threadIdx.x, lane = tid & 63, wave = tid >> 6;

    // staging role: threads 0-255 stage A, 256-511 stage B
    const int half = tid >> 8;
    const int t9 = tid & 255;
    const int ptq = t9 >> 4;          // token pair 0..15
    const int pi = (t9 & 15) * 8;     // col group base
    const unsigned short* sg = half ? Bg : Ag;
    const int nb = half ? j0 : i0;
    unsigned int* dst = (unsigned int*)(half ? Bs2 : As);
    const unsigned short* gp = sg + (size_t)(t0 + ptq * 2) * 256 + nb + pi;

    // wave output tile: 64 rows (i) x 32 cols (j)
    const int wr = (wave >> 2) * 64, wc = (wave & 3) * 32;
    const int fr = lane & 15, fkb = lane >> 4;

    f32x4 acc[4][2];
#pragma unroll
    for (int i = 0; i < 4; i++)
#pragma unroll
        for (int j = 0; j < 2; j++) acc[i][j] = (f32x4){0.f, 0.f, 0.f, 0.f};

    uint4 u0 = *(const uint4*)gp;
    uint4 u1 = *(const uint4*)(gp + 256);
    gp += 32 * 256;

    for (int it = 0; it < 32; it++) {
        // transpose-write: pack (token 2q, 2q+1) per col, swizzled slot
        const unsigned int* w0 = (const unsigned int*)&u0;
        const unsigned int* w1 = (const unsigned int*)&u1;
#pragma unroll
        for (int ii = 0; ii < 8; ii++) {
            unsigned int lo = (w0[ii >> 1] >> (16 * (ii & 1))) & 0xFFFFu;
            unsigned int hi = (w1[ii >> 1] >> (16 * (ii & 1))) & 0xFFFFu;
            const int col = pi + ii;
            const int s2 = ((col >> 3) ^ col) & 3;
            const int s4 = ((col >> 2) ^ (col >> 5)) & 1;
            dst[col * 32 + (ptq ^ (s2 << 2) ^ (s4 << 4))] = lo | (hi << 16);
        }
        __syncthreads();
        if (it < 31) {  // prefetch next K-chunk; latency hides under MFMA phase
            u0 = *(const uint4*)gp;
            u1 = *(const uint4*)(gp + 256);
            gp += 32 * 256;
        }
        bf16x8 af[4], bfr[2];
#pragma unroll
        for (int i = 0; i < 4; i++) {
            const int col = wr + i * 16 + fr;
            const int s2 = ((col >> 3) ^ col) & 3;
            const int s4 = ((col >> 2) ^ (col >> 5)) & 1;
            af[i] = *(const bf16x8*)&As[col * 64 + (fkb ^ s2 ^ (s4 << 2)) * 8];
        }
#pragma unroll
        for (int j = 0; j < 2; j++) {
            const int col = wc + j * 16 + fr;
            const int s2 = ((col >> 3) ^ col) & 3;
            const int s4 = ((col >> 2) ^ (col >> 5)) & 1;
            bfr[j] = *(const bf16x8*)&Bs2[col * 64 + (fkb ^ s2 ^ (s4 << 2)) * 8];
        }
#pragma unroll
        for (int i = 0; i < 4; i++)
#pragma unroll
            for (int j = 0; j < 2; j++)
                acc[i][j] = __builtin_amdgcn_mfma_f32_16x16x32_bf16(
                    af[i], bfr[j], acc[i][j], 0, 0, 0);
        __syncthreads();
    }

    float* P = pbuf + (size_t)((layer << 5) + zc) * 65536;
    const int r0 = fkb * 4;
#pragma unroll
    for (int mi = 0; mi < 4; mi++)
#pragma unroll
        for (int ni = 0; ni < 2; ni++) {
            f32x4 c = acc[mi][ni];
#pragma unroll
            for (int r = 0; r < 4; r++)
                P[(size_t)(i0 + wr + mi * 16 + r0 + r) * 256 +
                  (j0 + wc + ni * 16 + fr)] = c[r];
        }
}

// ---------------------------------------------------------------------------
// gradstep: reduce pbuf (32 chunks) -> g; surprises; AdamW for W and b.
// blocks 0..511: weights (256 threads each). block 512: biases.
// ---------------------------------------------------------------------------
__global__ __launch_bounds__(256) void gradstep_k(
    const float* __restrict__ pbuf, const float* __restrict__ Ws,
    const float* __restrict__ bs, const float* __restrict__ accB,
    unsigned short* __restrict__ nWt, float* __restrict__ nb,
    float* __restrict__ outSW, float* __restrict__ outSb) {
    const int bi = blockIdx.x;
    if (bi < 512) {
        const int idx = bi * 256 + threadIdx.x;  // 0..131071
        const int layer = idx >> 16, rc = idx & 65535;
        const float* p = pbuf + (size_t)layer * 32 * 65536 + rc;
        float g = 0.f;
#pragma unroll 8
        for (int c = 0; c < 32; c++) g += p[(size_t)c * 65536];
        outSW[idx] = -g;
        float nw = Ws[idx] * (1.f - LRc * WDc) - LRc * g / (fabsf(g) + EPSc);
        const int l = idx >> 16, k = (idx >> 8) & 255, n = idx & 255;
        nWt[(size_t)l * 65536 + n * 256 + k] = f2b(nw);
    } else {
        for (int i = threadIdx.x; i < 512; i += 256) {
            float g = accB[i];
            outSb[i] = -g;
            nb[i] = bs[i] * (1.f - LRc * WDc) - LRc * g / (fabsf(g) + EPSc);
        }
    }
}

// ---------------------------------------------------------------------------
// prep_w: blocks 0..1535 -> weight transpose+cvt (z=0..4) / cvt (z=5)
//         block 1536     -> zero accB[512]
// ---------------------------------------------------------------------------
__global__ __launch_bounds__(256) void prep_w_k(
    const float* __restrict__ Wk, const float* __restrict__ Wq,
    const float* __restrict__ Wv, const float* __restrict__ Ws,
    unsigned short* __restrict__ wt, float* __restrict__ accB) {
    const int bi = blockIdx.x;
    if (bi < 1536) {
        const int z = bi >> 8;
        const int idx = (bi & 255) * 256 + threadIdx.x;  // 0..65535
        const float* src = z == 0 ? Wk : z == 1 ? Wq : z == 2 ? Wv
                         : z == 3 ? Ws : Ws + 65536;
        unsigned short* dst = wt + (size_t)z * 65536;
        float v = src[idx];
        if (z == 5)
            dst[idx] = f2b(v);
        else
            dst[(idx & 255) * 256 + (idx >> 8)] = f2b(v);
    } else {
        accB[threadIdx.x] = 0.f;
        accB[threadIdx.x + 256] = 0.f;
    }
}

extern "C" void kernel_launch(void* const* d_in, const int* in_sizes, int n_in,
                              void* d_out, int out_size, void* d_ws,
                              size_t ws_size, hipStream_t stream) {
    const float* x = (const float*)d_in[0];
    const float* Wk = (const float*)d_in[1];
    const float* Wq = (const float*)d_in[2];
    const float* Wv = (const float*)d_in[3];
    const float* Wlr = (const float*)d_in[4];
    const float* blr = (const float*)d_in[5];
    const float* Ws = (const float*)d_in[6];
    const float* bs = (const float*)d_in[7];

    unsigned short* S = (unsigned short*)d_ws;
    unsigned short* xb = S + 0 * NM;  // r1b scratch (retrieval intermediate)
    unsigned short* Kb = S + 1 * NM;
    unsigned short* Qb = S + 2 * NM;
    unsigned short* Vb = S + 3 * NM;
    unsigned short* z0b = S + 4 * NM;
    unsigned short* h1b = S + 5 * NM;
    unsigned short* dz1b = S + 6 * NM;
    unsigned short* dh2b = S + 7 * NM;
    unsigned short* dz0b = S + 8 * NM;
    float* pbuf = (float*)(S + 9 * NM);  // 16 MB (slot 9): 2 layers x 32 chunks
    unsigned short* r1b = xb;

    unsigned short* wt = S + 11 * NM;
    unsigned short* W0t = wt + 3 * 65536;
    unsigned short* W1t = wt + 4 * 65536;
    unsigned short* W1b = wt + 5 * 65536;
    unsigned short* nW0t = wt + 6 * 65536;
    unsigned short* nW1t = wt + 7 * 65536;
    float* ft = (float*)(wt + 8 * 65536);
    float* alr = ft;              // 32768
    float* accB = ft + 32768;     // 512
    float* nb = accB + 512;       // 512

    float* out_ret = (float*)d_out;
    float* out_sW = out_ret + NM;
    float* out_sb = out_sW + 131072;

    dim3 blk5(512);
    dim3 blk(256);
    dim3 g_tall(2, 256);

    // prep: weight transpose/cvt + zero accB (x handled inside wgemm3_k)
    prep_w_k<<<1537, blk, 0, stream>>>(Wk, Wq, Wv, Ws, wt, accB);

    // projections K,Q,V (+ x->bf16 conversion + alr), z-loop inside block
    wgemm3_k<<<g_tall, blk5, 0, stream>>>(x, Wlr, blr, wt, Kb, Qb, Vb, alr);

    // fwd layer 0: h1 = K + silu(K@W0 + b0); saves z0
    wgemm_k<1><<<g_tall, blk5, 0, stream>>>(Kb, W0t, bs, nullptr, nullptr,
                                            nullptr, nullptr, nullptr, h1b,
                                            nullptr, z0b, nullptr);

    // fwd layer 1 + bwd elementwise: dz1, dh2 (+ colsum dz1 -> accB[256..])
    wgemm_k<5><<<g_tall, blk5, 0, stream>>>(h1b, W1t, bs + 256, nullptr,
                                            nullptr, Vb, alr, accB + 256,
                                            dz1b, nullptr, nullptr, dh2b);

    // bwd layer 0: dz0 = (dz1@W1^T + dh2) * dsilu(z0) (+ colsum -> accB[0..])
    wgemm_k<2><<<g_tall, blk5, 0, stream>>>(dz1b, W1b, nullptr, dh2b, z0b,
                                            nullptr, nullptr, accB, dz0b,
                                            nullptr, nullptr, nullptr);

    // weight grads: swizzled transpose-on-load split-K partials
    rgemm_k<<<dim3(2, 2, 64), blk5, 0, stream>>>(Kb, h1b, dz0b, dz1b, pbuf);

    // reduce + surprises + AdamW (W and b) in one dispatch
    gradstep_k<<<513, blk, 0, stream>>>(pbuf, Ws, bs, accB, nW0t, nb, out_sW,
                                        out_sb);

    // retrieved with new weights (two tall passes)
    wgemm_k<3><<<g_tall, blk5, 0, stream>>>(Qb, nW0t, nb, nullptr, nullptr,
                                            nullptr, nullptr, nullptr, r1b,
                                            nullptr, nullptr, nullptr);
    wgemm_k<4><<<g_tall, blk5, 0, stream>>>(r1b, nW1t, nb + 256, nullptr,
                                            nullptr, nullptr, nullptr, nullptr,
                                            nullptr, out_ret, nullptr, nullptr);
}